// Round 3
// baseline (2215.519 us; speedup 1.0000x reference)
//
#include <hip/hip_runtime.h>
#include <hip/hip_bf16.h>
#include <math.h>

// ---------- types ----------
typedef __bf16 bf16x8 __attribute__((ext_vector_type(8)));
typedef __bf16 bf16x4 __attribute__((ext_vector_type(4)));
typedef float  floatx4 __attribute__((ext_vector_type(4)));

#define D_MODEL 1024
#define SEQ     2048
#define NHEAD   16
#define HD      64

__device__ __forceinline__ void async16(const void* g, void* l) {
  __builtin_amdgcn_global_load_lds((const __attribute__((address_space(1))) void*)g,
                                   (__attribute__((address_space(3))) void*)l, 16, 0, 0);
}

// ---------- LayerNorm: fp32 row(1024) -> bf16 (or fp32 for final) ----------
template<bool OUT_BF16>
__global__ __launch_bounds__(256)
void ln_kernel(const float* __restrict__ x, const float* __restrict__ w,
               const float* __restrict__ b, void* __restrict__ out)
{
  const int row = blockIdx.x;
  const int tid = threadIdx.x;
  const floatx4 f = *(const floatx4*)(x + (size_t)row * D_MODEL + tid * 4);
  float s = f[0] + f[1] + f[2] + f[3];
  #pragma unroll
  for (int off = 1; off < 64; off <<= 1) s += __shfl_xor(s, off);
  __shared__ float red[8];
  const int wv = tid >> 6;
  if ((tid & 63) == 0) red[wv] = s;
  __syncthreads();
  const float mu = (red[0] + red[1] + red[2] + red[3]) * (1.0f / 1024.0f);
  float d0 = f[0] - mu, d1 = f[1] - mu, d2 = f[2] - mu, d3 = f[3] - mu;
  float ss = d0 * d0 + d1 * d1 + d2 * d2 + d3 * d3;
  #pragma unroll
  for (int off = 1; off < 64; off <<= 1) ss += __shfl_xor(ss, off);
  if ((tid & 63) == 0) red[4 + wv] = ss;
  __syncthreads();
  const float rstd = rsqrtf((red[4] + red[5] + red[6] + red[7]) * (1.0f / 1024.0f) + 1e-5f);
  const floatx4 wv4 = *(const floatx4*)(w + tid * 4);
  const floatx4 bv4 = *(const floatx4*)(b + tid * 4);
  const float y0 = d0 * rstd * wv4[0] + bv4[0];
  const float y1 = d1 * rstd * wv4[1] + bv4[1];
  const float y2 = d2 * rstd * wv4[2] + bv4[2];
  const float y3 = d3 * rstd * wv4[3] + bv4[3];
  if (OUT_BF16) {
    bf16x4 o = { (__bf16)y0, (__bf16)y1, (__bf16)y2, (__bf16)y3 };
    *(bf16x4*)((__bf16*)out + (size_t)row * D_MODEL + tid * 4) = o;
  } else {
    floatx4 o = { y0, y1, y2, y3 };
    *(floatx4*)((float*)out + (size_t)row * D_MODEL + tid * 4) = o;
  }
}

// ---------- GEMM: C[M,N] = epi(A[M,K](bf16) @ W[N,K](fp32)^T + bias) ----------
#define EPI_GELU 1
#define EPI_RES  2
#define EPI_QKV  3

template<int MODE>
__global__ __launch_bounds__(256, 2)
void gemm_kernel(const __bf16* __restrict__ A, const float* __restrict__ W,
                 const float* __restrict__ bias, void* out,
                 const float* __restrict__ res, __bf16* __restrict__ vT,
                 int M, int N, int K)
{
  __shared__ __align__(16) __bf16 As[128][32];  // 8 KB
  __shared__ __align__(16) __bf16 Ws[128][32];  // 8 KB
  const int tid = threadIdx.x;
  const int lane = tid & 63, w = tid >> 6;
  const int wr = w >> 1, wc = w & 1;
  const int quad = lane >> 4, r = lane & 15;
  const int m0 = blockIdx.x * 128, n0 = blockIdx.y * 128;

  floatx4 acc[4][4] = {};

  const __bf16* Ab = A + (size_t)m0 * K;
  const float*  Wb = W + (size_t)n0 * K;
  const int arow = tid >> 2, ac = (tid & 3) * 8;   // A: 16B chunks, lane*16 contiguous
  const int wrow = tid >> 3, wc4 = (tid & 7) * 4;  // W: float4 chunks -> bf16x4 ds_write

  for (int k0 = 0; k0 < K; k0 += 32) {
    async16(Ab + (size_t)arow * K + k0 + ac, &As[arow][ac]);
    async16(Ab + (size_t)(arow + 64) * K + k0 + ac, &As[arow + 64][ac]);
    #pragma unroll
    for (int i = 0; i < 4; ++i) {
      const int rw = wrow + 32 * i;
      const floatx4 f = *(const floatx4*)(Wb + (size_t)rw * K + k0 + wc4);
      bf16x4 h4 = { (__bf16)f[0], (__bf16)f[1], (__bf16)f[2], (__bf16)f[3] };
      *(bf16x4*)&Ws[rw][wc4] = h4;
    }
    __syncthreads();
    bf16x8 af[4];
    #pragma unroll
    for (int mi = 0; mi < 4; ++mi)
      af[mi] = *(const bf16x8*)&As[wr * 64 + mi * 16 + r][quad * 8];
    #pragma unroll
    for (int ni = 0; ni < 4; ++ni) {
      bf16x8 bf = *(const bf16x8*)&Ws[wc * 64 + ni * 16 + r][quad * 8];
      #pragma unroll
      for (int mi = 0; mi < 4; ++mi)
        acc[mi][ni] = __builtin_amdgcn_mfma_f32_16x16x32_bf16(af[mi], bf, acc[mi][ni], 0, 0, 0);
    }
    __syncthreads();
  }

  // epilogue: C/D layout col=lane&15, row=quad*4+reg (m89/m91 verified)
  #pragma unroll
  for (int ni = 0; ni < 4; ++ni) {
    const int nn = n0 + wc * 64 + ni * 16 + r;
    const float bv = bias[nn];
    #pragma unroll
    for (int mi = 0; mi < 4; ++mi) {
      #pragma unroll
      for (int v = 0; v < 4; ++v) {
        const int mm = m0 + wr * 64 + mi * 16 + quad * 4 + v;
        float val = acc[mi][ni][v] + bv;
        if (MODE == EPI_GELU) {
          val = 0.5f * val * (1.0f + erff(val * 0.70710678118654752f));
          ((__bf16*)out)[(size_t)mm * N + nn] = (__bf16)val;
        } else if (MODE == EPI_RES) {
          ((float*)out)[(size_t)mm * N + nn] = res[(size_t)mm * N + nn] + val;
        } else if (MODE == EPI_QKV) {
          if (nn < 2048) {
            ((__bf16*)out)[(size_t)mm * 2048 + nn] = (__bf16)val;
          } else {
            const int c = nn - 2048, hh = c >> 6, dd = c & 63;
            const int bb = mm >> 11, t = mm & 2047;
            vT[(size_t)((bb * 16 + hh) * 64 + dd) * 2048 + t] = (__bf16)val;
          }
        }
      }
    }
  }
}

// ---------- Flash attention with ALiBi + causal ----------
// grid: x = T/64 q-tiles, y = B*H. 4 waves, wave owns 16 q rows.
__global__ __launch_bounds__(256, 2)
void attn_kernel(const __bf16* __restrict__ qk,  // [B*T][2048]: cols 0..1023 Q, 1024..2047 K
                 const __bf16* __restrict__ vT,  // [(b*16+h)*64+d][2048]
                 __bf16* __restrict__ out)       // [B*T][1024]
{
  __shared__ __align__(16) __bf16 Qs[64][64];    // 8 KB
  __shared__ __align__(16) __bf16 Ks[128][64];   // 16 KB
  __shared__ __align__(16) __bf16 Vs[64][128];   // 16 KB  (Vs[d][key])
  __shared__ __align__(16) __bf16 Ps[4][16][128];// 16 KB  wave-private
  const int tid = threadIdx.x, lane = tid & 63, w = tid >> 6;
  const int quad = lane >> 4, r = lane & 15;
  const int q0 = blockIdx.x * 64;
  const int bh = blockIdx.y, b = bh >> 4, h = bh & 15;

  { // stage Q: 64 rows x 128B
    const __bf16* qb = qk + ((size_t)(b * SEQ + q0)) * 2048 + h * 64;
    const int row = tid >> 3, c = (tid & 7) * 8;
    async16(qb + (size_t)row * 2048 + c, &Qs[row][c]);
    async16(qb + (size_t)(row + 32) * 2048 + c, &Qs[row + 32][c]);
  }
  __syncthreads();
  bf16x8 qf[2];
  qf[0] = *(const bf16x8*)&Qs[w * 16 + r][quad * 8];
  qf[1] = *(const bf16x8*)&Qs[w * 16 + r][32 + quad * 8];

  float m_i[4], l_i[4];
  floatx4 o[4] = {};
  #pragma unroll
  for (int v = 0; v < 4; ++v) { m_i[v] = -INFINITY; l_i[v] = 0.0f; }
  const float slope = exp2f(-0.5f * (float)(h + 1));
  int qrow[4];
  #pragma unroll
  for (int v = 0; v < 4; ++v) qrow[v] = q0 + w * 16 + quad * 4 + v;

  const __bf16* kb0 = qk + ((size_t)(b * SEQ)) * 2048 + 1024 + h * 64;
  const __bf16* vb0 = vT + ((size_t)(bh * 64)) * 2048;
  const int krow = tid >> 3, kc = (tid & 7) * 8;
  const int vrow = tid >> 4, vc = (tid & 15) * 8;
  const int ktEnd = (q0 + 63) >> 7;

  for (int kt = 0; kt <= ktEnd; ++kt) {
    const int kbase = kt << 7;
    #pragma unroll
    for (int i = 0; i < 4; ++i)
      async16(kb0 + (size_t)(kbase + krow + 32 * i) * 2048 + kc, &Ks[krow + 32 * i][kc]);
    #pragma unroll
    for (int i = 0; i < 4; ++i)
      async16(vb0 + (size_t)(vrow + 16 * i) * 2048 + kbase + vc, &Vs[vrow + 16 * i][vc]);
    __syncthreads();

    // S = Q K^T : wave tile 16 x 128
    floatx4 s[8];
    #pragma unroll
    for (int ni = 0; ni < 8; ++ni) {
      floatx4 z = { 0.0f, 0.0f, 0.0f, 0.0f };
      s[ni] = z;
      bf16x8 k0f = *(const bf16x8*)&Ks[ni * 16 + r][quad * 8];
      bf16x8 k1f = *(const bf16x8*)&Ks[ni * 16 + r][32 + quad * 8];
      s[ni] = __builtin_amdgcn_mfma_f32_16x16x32_bf16(qf[0], k0f, s[ni], 0, 0, 0);
      s[ni] = __builtin_amdgcn_mfma_f32_16x16x32_bf16(qf[1], k1f, s[ni], 0, 0, 0);
    }
    // scale + alibi + causal, row max
    float mrow[4] = { -INFINITY, -INFINITY, -INFINITY, -INFINITY };
    #pragma unroll
    for (int ni = 0; ni < 8; ++ni) {
      const int key = kbase + ni * 16 + r;
      #pragma unroll
      for (int v = 0; v < 4; ++v) {
        float sv = s[ni][v] * 0.125f + slope * (float)(key - qrow[v]);
        sv = (key <= qrow[v]) ? sv : -INFINITY;
        s[ni][v] = sv;
        mrow[v] = fmaxf(mrow[v], sv);
      }
    }
    #pragma unroll
    for (int off = 1; off < 16; off <<= 1) {
      #pragma unroll
      for (int v = 0; v < 4; ++v) mrow[v] = fmaxf(mrow[v], __shfl_xor(mrow[v], off));
    }
    float alpha[4], rsum[4];
    #pragma unroll
    for (int v = 0; v < 4; ++v) {
      const float mn = fmaxf(m_i[v], mrow[v]);
      alpha[v] = __expf(m_i[v] - mn);   // first tile: exp(-inf)=0
      m_i[v] = mn;
      rsum[v] = 0.0f;
    }
    #pragma unroll
    for (int ni = 0; ni < 8; ++ni) {
      #pragma unroll
      for (int v = 0; v < 4; ++v) {
        const float p = __expf(s[ni][v] - m_i[v]);  // masked -> 0; p <= 1 by construction
        rsum[v] += p;
        Ps[w][quad * 4 + v][ni * 16 + r] = (__bf16)p;
      }
    }
    #pragma unroll
    for (int off = 1; off < 16; off <<= 1) {
      #pragma unroll
      for (int v = 0; v < 4; ++v) rsum[v] += __shfl_xor(rsum[v], off);
    }
    #pragma unroll
    for (int v = 0; v < 4; ++v) l_i[v] = l_i[v] * alpha[v] + rsum[v];
    #pragma unroll
    for (int ni = 0; ni < 4; ++ni) {
      #pragma unroll
      for (int v = 0; v < 4; ++v) o[ni][v] *= alpha[v];
    }
    // O += P V : P in A-layout from wave-private LDS (same-wave DS ops are in order)
    #pragma unroll
    for (int ks = 0; ks < 4; ++ks) {
      bf16x8 pf = *(const bf16x8*)&Ps[w][r][ks * 32 + quad * 8];
      #pragma unroll
      for (int ni = 0; ni < 4; ++ni) {
        bf16x8 vf = *(const bf16x8*)&Vs[ni * 16 + r][ks * 32 + quad * 8];
        o[ni] = __builtin_amdgcn_mfma_f32_16x16x32_bf16(pf, vf, o[ni], 0, 0, 0);
      }
    }
    __syncthreads();
  }

  __bf16* ob = out + ((size_t)(b * SEQ + q0 + w * 16)) * D_MODEL + h * 64;
  #pragma unroll
  for (int ni = 0; ni < 4; ++ni) {
    #pragma unroll
    for (int v = 0; v < 4; ++v)
      ob[(size_t)(quad * 4 + v) * D_MODEL + ni * 16 + r] = (__bf16)(o[ni][v] / l_i[v]);
  }
}

// ---------- driver ----------
extern "C" void kernel_launch(void* const* d_in, const int* in_sizes, int n_in,
                              void* d_out, int out_size, void* d_ws, size_t ws_size,
                              hipStream_t stream)
{
  (void)in_sizes; (void)n_in; (void)out_size; (void)ws_size;
  const float* x    = (const float*)d_in[0];
  const float* inW  = (const float*)d_in[1];
  const float* inB  = (const float*)d_in[2];
  const float* outW = (const float*)d_in[3];
  const float* outB = (const float*)d_in[4];
  const float* f1W  = (const float*)d_in[5];
  const float* f1B  = (const float*)d_in[6];
  const float* f2W  = (const float*)d_in[7];
  const float* f2B  = (const float*)d_in[8];
  const float* ln1W = (const float*)d_in[9];
  const float* ln1B = (const float*)d_in[10];
  const float* ln2W = (const float*)d_in[11];
  const float* ln2B = (const float*)d_in[12];
  const float* fnW  = (const float*)d_in[13];
  const float* fnB  = (const float*)d_in[14];

  char* ws = (char*)d_ws;
  float*  x_cur = (float*)(ws);                    // 16.78 MB fp32 residual
  __bf16* xn    = (__bf16*)(ws + 16777216);        //  8.39 MB
  __bf16* qk    = (__bf16*)(ws + 25165824);        // 16.78 MB
  __bf16* vT    = (__bf16*)(ws + 41943040);        //  8.39 MB
  __bf16* attn  = (__bf16*)(ws + 50331648);        //  8.39 MB
  __bf16* hbuf  = (__bf16*)(ws + 25165824);        // 33.55 MB, aliases qk/vT/attn (dead by FFN1)
  // total footprint: 56 MB

  hipMemcpyAsync(x_cur, x, (size_t)16777216, hipMemcpyDeviceToDevice, stream);

  for (int i = 0; i < 4; ++i) {
    ln_kernel<true><<<dim3(4096), dim3(256), 0, stream>>>(
        x_cur, ln1W + i * 1024, ln1B + i * 1024, xn);
    gemm_kernel<EPI_QKV><<<dim3(32, 24), dim3(256), 0, stream>>>(
        xn, inW + (size_t)i * 3072 * 1024, inB + (size_t)i * 3072,
        qk, nullptr, vT, 4096, 3072, 1024);
    attn_kernel<<<dim3(32, 32), dim3(256), 0, stream>>>(qk, vT, attn);
    gemm_kernel<EPI_RES><<<dim3(32, 8), dim3(256), 0, stream>>>(
        attn, outW + (size_t)i * 1024 * 1024, outB + (size_t)i * 1024,
        x_cur, x_cur, nullptr, 4096, 1024, 1024);
    ln_kernel<true><<<dim3(4096), dim3(256), 0, stream>>>(
        x_cur, ln2W + i * 1024, ln2B + i * 1024, xn);
    gemm_kernel<EPI_GELU><<<dim3(32, 32), dim3(256), 0, stream>>>(
        xn, f1W + (size_t)i * 4096 * 1024, f1B + (size_t)i * 4096,
        hbuf, nullptr, nullptr, 4096, 4096, 1024);
    gemm_kernel<EPI_RES><<<dim3(32, 8), dim3(256), 0, stream>>>(
        hbuf, f2W + (size_t)i * 1024 * 4096, f2B + (size_t)i * 1024,
        x_cur, x_cur, nullptr, 4096, 1024, 4096);
  }
  ln_kernel<false><<<dim3(4096), dim3(256), 0, stream>>>(x_cur, fnW, fnB, d_out);
}

// Round 4
// 1795.502 us; speedup vs baseline: 1.2339x; 1.2339x over previous
//
#include <hip/hip_runtime.h>
#include <hip/hip_bf16.h>
#include <math.h>

// ---------- types ----------
typedef __bf16 bf16x8 __attribute__((ext_vector_type(8)));
typedef __bf16 bf16x4 __attribute__((ext_vector_type(4)));
typedef float  floatx4 __attribute__((ext_vector_type(4)));

#define D_MODEL 1024
#define SEQ     2048
#define NHEAD   16
#define HD      64

__device__ __forceinline__ void async16(const void* g, void* l) {
  __builtin_amdgcn_global_load_lds((const __attribute__((address_space(1))) void*)g,
                                   (__attribute__((address_space(3))) void*)l, 16, 0, 0);
}

// ---------- LayerNorm: fp32 row(1024) -> bf16 (or fp32 for final) ----------
template<bool OUT_BF16>
__global__ __launch_bounds__(256)
void ln_kernel(const float* __restrict__ x, const float* __restrict__ w,
               const float* __restrict__ b, void* __restrict__ out)
{
  const int row = blockIdx.x;
  const int tid = threadIdx.x;
  const floatx4 f = *(const floatx4*)(x + (size_t)row * D_MODEL + tid * 4);
  float s = f[0] + f[1] + f[2] + f[3];
  #pragma unroll
  for (int off = 1; off < 64; off <<= 1) s += __shfl_xor(s, off);
  __shared__ float red[8];
  const int wv = tid >> 6;
  if ((tid & 63) == 0) red[wv] = s;
  __syncthreads();
  const float mu = (red[0] + red[1] + red[2] + red[3]) * (1.0f / 1024.0f);
  float d0 = f[0] - mu, d1 = f[1] - mu, d2 = f[2] - mu, d3 = f[3] - mu;
  float ss = d0 * d0 + d1 * d1 + d2 * d2 + d3 * d3;
  #pragma unroll
  for (int off = 1; off < 64; off <<= 1) ss += __shfl_xor(ss, off);
  if ((tid & 63) == 0) red[4 + wv] = ss;
  __syncthreads();
  const float rstd = rsqrtf((red[4] + red[5] + red[6] + red[7]) * (1.0f / 1024.0f) + 1e-5f);
  const floatx4 wv4 = *(const floatx4*)(w + tid * 4);
  const floatx4 bv4 = *(const floatx4*)(b + tid * 4);
  const float y0 = d0 * rstd * wv4[0] + bv4[0];
  const float y1 = d1 * rstd * wv4[1] + bv4[1];
  const float y2 = d2 * rstd * wv4[2] + bv4[2];
  const float y3 = d3 * rstd * wv4[3] + bv4[3];
  if (OUT_BF16) {
    bf16x4 o = { (__bf16)y0, (__bf16)y1, (__bf16)y2, (__bf16)y3 };
    *(bf16x4*)((__bf16*)out + (size_t)row * D_MODEL + tid * 4) = o;
  } else {
    floatx4 o = { y0, y1, y2, y3 };
    *(floatx4*)((float*)out + (size_t)row * D_MODEL + tid * 4) = o;
  }
}

// ---------- GEMM: C[M,N] = epi(A[M,K](bf16) @ W[N,K](fp32)^T + bias) ----------
#define EPI_GELU 1
#define EPI_RES  2
#define EPI_QKV  3

// NT = 128 (waves 2x2 of 64x64) or 64 (waves 2x2 of 64x32; doubles block count for small N)
template<int MODE, int NT>
__global__ __launch_bounds__(256, 2)
void gemm_kernel(const __bf16* __restrict__ A, const float* __restrict__ W,
                 const float* __restrict__ bias, void* out,
                 const float* __restrict__ res, __bf16* __restrict__ vT,
                 int M, int N, int K)
{
  __shared__ __align__(16) __bf16 As[128][32];  // 8 KB (64B rows: conflict-free b128)
  __shared__ __align__(16) __bf16 Ws[NT][32];
  const int tid = threadIdx.x;
  const int lane = tid & 63, w = tid >> 6;
  const int wr = w >> 1, wc = w & 1;
  const int quad = lane >> 4, r = lane & 15;
  constexpr int NACC = NT / 32;
  const int m0 = blockIdx.x * 128, n0 = blockIdx.y * NT;

  floatx4 acc[4][NACC] = {};

  const __bf16* Ab = A + (size_t)m0 * K;
  const float*  Wb = W + (size_t)n0 * K;
  const int arow = tid >> 2, ac = (tid & 3) * 8;   // A: 16B chunks, lane*16 contiguous
  const int wrow = tid >> 3, wc4 = (tid & 7) * 4;  // W: float4 chunks -> bf16x4 ds_write

  for (int k0 = 0; k0 < K; k0 += 32) {
    async16(Ab + (size_t)arow * K + k0 + ac, &As[arow][ac]);
    async16(Ab + (size_t)(arow + 64) * K + k0 + ac, &As[arow + 64][ac]);
    #pragma unroll
    for (int i = 0; i < NT / 32; ++i) {
      const int rw = wrow + 32 * i;
      const floatx4 f = *(const floatx4*)(Wb + (size_t)rw * K + k0 + wc4);
      bf16x4 h4 = { (__bf16)f[0], (__bf16)f[1], (__bf16)f[2], (__bf16)f[3] };
      *(bf16x4*)&Ws[rw][wc4] = h4;
    }
    __syncthreads();
    bf16x8 af[4];
    #pragma unroll
    for (int mi = 0; mi < 4; ++mi)
      af[mi] = *(const bf16x8*)&As[wr * 64 + mi * 16 + r][quad * 8];
    #pragma unroll
    for (int ni = 0; ni < NACC; ++ni) {
      bf16x8 bf = *(const bf16x8*)&Ws[wc * (NT / 2) + ni * 16 + r][quad * 8];
      #pragma unroll
      for (int mi = 0; mi < 4; ++mi)
        acc[mi][ni] = __builtin_amdgcn_mfma_f32_16x16x32_bf16(af[mi], bf, acc[mi][ni], 0, 0, 0);
    }
    __syncthreads();
  }

  // epilogue: C/D layout col=lane&15, row=quad*4+reg
  #pragma unroll
  for (int ni = 0; ni < NACC; ++ni) {
    const int nn = n0 + wc * (NT / 2) + ni * 16 + r;
    const float bv = bias[nn];
    #pragma unroll
    for (int mi = 0; mi < 4; ++mi) {
      #pragma unroll
      for (int v = 0; v < 4; ++v) {
        const int mm = m0 + wr * 64 + mi * 16 + quad * 4 + v;
        float val = acc[mi][ni][v] + bv;
        if (MODE == EPI_GELU) {
          val = 0.5f * val * (1.0f + erff(val * 0.70710678118654752f));
          ((__bf16*)out)[(size_t)mm * N + nn] = (__bf16)val;
        } else if (MODE == EPI_RES) {
          ((float*)out)[(size_t)mm * N + nn] = res[(size_t)mm * N + nn] + val;
        } else if (MODE == EPI_QKV) {
          if (nn < 2048) {
            ((__bf16*)out)[(size_t)mm * 2048 + nn] = (__bf16)val;
          } else {
            const int c = nn - 2048, hh = c >> 6, dd = c & 63;
            const int bb = mm >> 11, t = mm & 2047;
            vT[(size_t)((bb * 16 + hh) * 64 + dd) * 2048 + t] = (__bf16)val;
          }
        }
      }
    }
  }
}

// ---------- Flash attention, transposed-MFMA formulation ----------
// S^T = K.Q^T (col = query = lane&15), P^T built in registers via shuffles,
// O^T = V^T.P^T. All LDS tiles have 64B rows -> conflict-free ds_read_b128.
// grid: x = 32 q-tiles (LPT-reversed), y = B*H. 4 waves; wave w owns queries q0+w*16..+15.
__global__ __launch_bounds__(256, 4)
void attn_kernel(const __bf16* __restrict__ qk,  // [B*T][2048]: cols 0..1023 Q, 1024..2047 K
                 const __bf16* __restrict__ vT,  // [(b*16+h)*64+d][2048]
                 __bf16* __restrict__ out)       // [B*T][1024]
{
  __shared__ __align__(16) __bf16 Qs[2][64][32];   // [d-half][q][d]    8 KB
  __shared__ __align__(16) __bf16 Ks[2][128][32];  // [d-half][key][d] 16 KB
  __shared__ __align__(16) __bf16 Vs[4][64][32];   // [key-blk][d][key]16 KB  (40 KB total)
  const int tid = threadIdx.x, lane = tid & 63, w = tid >> 6;
  const int quad = lane >> 4, r = lane & 15;
  const int qt = gridDim.x - 1 - blockIdx.x;       // LPT: longest blocks dispatch first
  const int q0 = qt * 64;
  const int bh = blockIdx.y, b = bh >> 4, h = bh & 15;

  { // stage Q both halves: chunk = tid, LDS offset tid*16 per array (wave-contiguous)
    const __bf16* qb = qk + ((size_t)(b * SEQ + q0)) * 2048 + h * 64;
    const int row = tid >> 2, c8 = (tid & 3) * 8;
    async16(qb + (size_t)row * 2048 + c8,      &Qs[0][row][c8]);
    async16(qb + (size_t)row * 2048 + 32 + c8, &Qs[1][row][c8]);
  }
  __syncthreads();
  const bf16x8 qf0 = *(const bf16x8*)&Qs[0][w * 16 + r][quad * 8];
  const bf16x8 qf1 = *(const bf16x8*)&Qs[1][w * 16 + r][quad * 8];

  const int q = q0 + w * 16 + r;                   // this lane's query row
  float m_i = -INFINITY, l_i = 0.0f;
  floatx4 ot[4] = {};
  const float slope = exp2f(-0.5f * (float)(h + 1));

  const __bf16* kb0 = qk + ((size_t)(b * SEQ)) * 2048 + 1024 + h * 64;
  const __bf16* vb0 = vT + ((size_t)(bh * 64)) * 2048;
  const int ktEnd = (q0 + 63) >> 7;

  for (int kt = 0; kt <= ktEnd; ++kt) {
    const int kbase = kt << 7;
    #pragma unroll
    for (int half = 0; half < 2; ++half) {
      #pragma unroll
      for (int rd = 0; rd < 2; ++rd) {
        const int c = rd * 256 + tid, row = c >> 2, c8 = (c & 3) * 8;
        async16(kb0 + (size_t)(kbase + row) * 2048 + half * 32 + c8, &Ks[half][row][c8]);
      }
    }
    #pragma unroll
    for (int rd = 0; rd < 4; ++rd) {
      const int c = rd * 256 + tid, kb = c >> 8, d = (c >> 2) & 63, c8 = (c & 3) * 8;
      async16(vb0 + (size_t)d * 2048 + kbase + kb * 32 + c8, &Vs[kb][d][c8]);
    }
    __syncthreads();

    // S^T tiles: st[t] covers keys kbase+t*16..+15; lane holds key=t*16+quad*4+v, q=r
    floatx4 st[8];
    #pragma unroll
    for (int t = 0; t < 8; ++t) {
      floatx4 z = { 0.0f, 0.0f, 0.0f, 0.0f };
      const bf16x8 kf0 = *(const bf16x8*)&Ks[0][t * 16 + r][quad * 8];
      const bf16x8 kf1 = *(const bf16x8*)&Ks[1][t * 16 + r][quad * 8];
      z = __builtin_amdgcn_mfma_f32_16x16x32_bf16(kf0, qf0, z, 0, 0, 0);
      st[t] = __builtin_amdgcn_mfma_f32_16x16x32_bf16(kf1, qf1, z, 0, 0, 0);
    }
    // scale + alibi + causal; per-query stats live in the 4 quad-mates (xor 16,32)
    float mloc = -INFINITY;
    #pragma unroll
    for (int t = 0; t < 8; ++t) {
      #pragma unroll
      for (int v = 0; v < 4; ++v) {
        const int key = kbase + t * 16 + quad * 4 + v;
        float sv = st[t][v] * 0.125f + slope * (float)(key - q);
        sv = (key <= q) ? sv : -INFINITY;
        st[t][v] = sv;
        mloc = fmaxf(mloc, sv);
      }
    }
    mloc = fmaxf(mloc, __shfl_xor(mloc, 16));
    mloc = fmaxf(mloc, __shfl_xor(mloc, 32));
    const float mn = fmaxf(m_i, mloc);
    const float alpha = __expf(m_i - mn);   // first tile: exp(-inf)=0
    m_i = mn;
    float rsum = 0.0f;
    #pragma unroll
    for (int t = 0; t < 8; ++t) {
      #pragma unroll
      for (int v = 0; v < 4; ++v) {
        const float p = __expf(st[t][v] - mn);
        st[t][v] = p;
        rsum += p;
      }
    }
    rsum += __shfl_xor(rsum, 16);
    rsum += __shfl_xor(rsum, 32);
    l_i = l_i * alpha + rsum;
    #pragma unroll
    for (int dt = 0; dt < 4; ++dt) ot[dt] *= alpha;

    // P^T B-frag per 32-key block: lane (r,quad) needs key kb*32+quad*8+j, col q=r.
    // source acc = 2kb+(quad>>1), reg = j&3, lane = r + 16*(2*(quad&1)+(j>>2))
    #pragma unroll
    for (int kb = 0; kb < 4; ++kb) {
      bf16x8 pf;
      #pragma unroll
      for (int j = 0; j < 8; ++j) {
        const int srcLane = r + 16 * (2 * (quad & 1) + (j >> 2));
        const float a0 = __shfl(st[2 * kb][j & 3], srcLane, 64);
        const float a1 = __shfl(st[2 * kb + 1][j & 3], srcLane, 64);
        pf[j] = (__bf16)((quad >= 2) ? a1 : a0);
      }
      #pragma unroll
      for (int dt = 0; dt < 4; ++dt) {
        const bf16x8 vf = *(const bf16x8*)&Vs[kb][dt * 16 + r][quad * 8];
        ot[dt] = __builtin_amdgcn_mfma_f32_16x16x32_bf16(vf, pf, ot[dt], 0, 0, 0);
      }
    }
    __syncthreads();
  }

  // O^T C-layout: col = q = r (lane), row = d = dt*16 + quad*4 + v -> bf16x4 stores
  const float linv = 1.0f / l_i;
  __bf16* ob = out + (size_t)(b * SEQ + q) * D_MODEL + h * 64;
  #pragma unroll
  for (int dt = 0; dt < 4; ++dt) {
    bf16x4 o4 = { (__bf16)(ot[dt][0] * linv), (__bf16)(ot[dt][1] * linv),
                  (__bf16)(ot[dt][2] * linv), (__bf16)(ot[dt][3] * linv) };
    *(bf16x4*)(ob + dt * 16 + quad * 4) = o4;
  }
}

// ---------- driver ----------
extern "C" void kernel_launch(void* const* d_in, const int* in_sizes, int n_in,
                              void* d_out, int out_size, void* d_ws, size_t ws_size,
                              hipStream_t stream)
{
  (void)in_sizes; (void)n_in; (void)out_size; (void)ws_size;
  const float* x    = (const float*)d_in[0];
  const float* inW  = (const float*)d_in[1];
  const float* inB  = (const float*)d_in[2];
  const float* outW = (const float*)d_in[3];
  const float* outB = (const float*)d_in[4];
  const float* f1W  = (const float*)d_in[5];
  const float* f1B  = (const float*)d_in[6];
  const float* f2W  = (const float*)d_in[7];
  const float* f2B  = (const float*)d_in[8];
  const float* ln1W = (const float*)d_in[9];
  const float* ln1B = (const float*)d_in[10];
  const float* ln2W = (const float*)d_in[11];
  const float* ln2B = (const float*)d_in[12];
  const float* fnW  = (const float*)d_in[13];
  const float* fnB  = (const float*)d_in[14];

  char* ws = (char*)d_ws;
  float*  x_cur = (float*)(ws);                    // 16.78 MB fp32 residual
  __bf16* xn    = (__bf16*)(ws + 16777216);        //  8.39 MB
  __bf16* qk    = (__bf16*)(ws + 25165824);        // 16.78 MB
  __bf16* vT    = (__bf16*)(ws + 41943040);        //  8.39 MB
  __bf16* attn  = (__bf16*)(ws + 50331648);        //  8.39 MB
  __bf16* hbuf  = (__bf16*)(ws + 25165824);        // 33.55 MB, aliases qk/vT/attn (dead by FFN1)
  // total footprint: 56 MB

  hipMemcpyAsync(x_cur, x, (size_t)16777216, hipMemcpyDeviceToDevice, stream);

  for (int i = 0; i < 4; ++i) {
    ln_kernel<true><<<dim3(4096), dim3(256), 0, stream>>>(
        x_cur, ln1W + i * 1024, ln1B + i * 1024, xn);
    gemm_kernel<EPI_QKV, 128><<<dim3(32, 24), dim3(256), 0, stream>>>(
        xn, inW + (size_t)i * 3072 * 1024, inB + (size_t)i * 3072,
        qk, nullptr, vT, 4096, 3072, 1024);
    attn_kernel<<<dim3(32, 32), dim3(256), 0, stream>>>(qk, vT, attn);
    gemm_kernel<EPI_RES, 64><<<dim3(32, 16), dim3(256), 0, stream>>>(
        attn, outW + (size_t)i * 1024 * 1024, outB + (size_t)i * 1024,
        x_cur, x_cur, nullptr, 4096, 1024, 1024);
    ln_kernel<true><<<dim3(4096), dim3(256), 0, stream>>>(
        x_cur, ln2W + i * 1024, ln2B + i * 1024, xn);
    gemm_kernel<EPI_GELU, 128><<<dim3(32, 32), dim3(256), 0, stream>>>(
        xn, f1W + (size_t)i * 4096 * 1024, f1B + (size_t)i * 4096,
        hbuf, nullptr, nullptr, 4096, 4096, 1024);
    gemm_kernel<EPI_RES, 64><<<dim3(32, 16), dim3(256), 0, stream>>>(
        hbuf, f2W + (size_t)i * 1024 * 4096, f2B + (size_t)i * 1024,
        x_cur, x_cur, nullptr, 4096, 1024, 4096);
  }
  ln_kernel<false><<<dim3(4096), dim3(256), 0, stream>>>(x_cur, fnW, fnB, d_out);
}

// Round 5
// 1612.569 us; speedup vs baseline: 1.3739x; 1.1134x over previous
//
#include <hip/hip_runtime.h>
#include <hip/hip_bf16.h>
#include <math.h>

// ---------- types ----------
typedef __bf16 bf16x8 __attribute__((ext_vector_type(8)));
typedef __bf16 bf16x4 __attribute__((ext_vector_type(4)));
typedef float  floatx4 __attribute__((ext_vector_type(4)));

#define D_MODEL 1024
#define SEQ     2048
#define NHEAD   16
#define HD      64

__device__ __forceinline__ void async16(const void* g, void* l) {
  __builtin_amdgcn_global_load_lds((const __attribute__((address_space(1))) void*)g,
                                   (__attribute__((address_space(3))) void*)l, 16, 0, 0);
}

// ---------- LayerNorm: fp32 row(1024) -> bf16 (or fp32 for final) ----------
template<bool OUT_BF16>
__global__ __launch_bounds__(256)
void ln_kernel(const float* __restrict__ x, const float* __restrict__ w,
               const float* __restrict__ b, void* __restrict__ out)
{
  const int row = blockIdx.x;
  const int tid = threadIdx.x;
  const floatx4 f = *(const floatx4*)(x + (size_t)row * D_MODEL + tid * 4);
  float s = f[0] + f[1] + f[2] + f[3];
  #pragma unroll
  for (int off = 1; off < 64; off <<= 1) s += __shfl_xor(s, off);
  __shared__ float red[8];
  const int wv = tid >> 6;
  if ((tid & 63) == 0) red[wv] = s;
  __syncthreads();
  const float mu = (red[0] + red[1] + red[2] + red[3]) * (1.0f / 1024.0f);
  float d0 = f[0] - mu, d1 = f[1] - mu, d2 = f[2] - mu, d3 = f[3] - mu;
  float ss = d0 * d0 + d1 * d1 + d2 * d2 + d3 * d3;
  #pragma unroll
  for (int off = 1; off < 64; off <<= 1) ss += __shfl_xor(ss, off);
  if ((tid & 63) == 0) red[4 + wv] = ss;
  __syncthreads();
  const float rstd = rsqrtf((red[4] + red[5] + red[6] + red[7]) * (1.0f / 1024.0f) + 1e-5f);
  const floatx4 wv4 = *(const floatx4*)(w + tid * 4);
  const floatx4 bv4 = *(const floatx4*)(b + tid * 4);
  const float y0 = d0 * rstd * wv4[0] + bv4[0];
  const float y1 = d1 * rstd * wv4[1] + bv4[1];
  const float y2 = d2 * rstd * wv4[2] + bv4[2];
  const float y3 = d3 * rstd * wv4[3] + bv4[3];
  if (OUT_BF16) {
    bf16x4 o = { (__bf16)y0, (__bf16)y1, (__bf16)y2, (__bf16)y3 };
    *(bf16x4*)((__bf16*)out + (size_t)row * D_MODEL + tid * 4) = o;
  } else {
    floatx4 o = { y0, y1, y2, y3 };
    *(floatx4*)((float*)out + (size_t)row * D_MODEL + tid * 4) = o;
  }
}

// ---------- GEMM: C[M,N] = epi(A[M,K](bf16) @ W[N,K](fp32)^T + bias) ----------
#define EPI_GELU 1
#define EPI_RES  2
#define EPI_QKV  3

// NT = 128 (waves 2x2 of 64x64) or 64 (waves 2x2 of 64x32; doubles block count for small N)
template<int MODE, int NT>
__global__ __launch_bounds__(256, 2)
void gemm_kernel(const __bf16* __restrict__ A, const float* __restrict__ W,
                 const float* __restrict__ bias, void* out,
                 const float* __restrict__ res, __bf16* __restrict__ vT,
                 int M, int N, int K)
{
  __shared__ __align__(16) __bf16 As[128][32];  // 8 KB (64B rows: conflict-free b128)
  __shared__ __align__(16) __bf16 Ws[NT][32];
  const int tid = threadIdx.x;
  const int lane = tid & 63, w = tid >> 6;
  const int wr = w >> 1, wc = w & 1;
  const int quad = lane >> 4, r = lane & 15;
  constexpr int NACC = NT / 32;
  const int m0 = blockIdx.x * 128, n0 = blockIdx.y * NT;

  floatx4 acc[4][NACC] = {};

  const __bf16* Ab = A + (size_t)m0 * K;
  const float*  Wb = W + (size_t)n0 * K;
  const int arow = tid >> 2, ac = (tid & 3) * 8;   // A: 16B chunks, lane*16 contiguous
  const int wrow = tid >> 3, wc4 = (tid & 7) * 4;  // W: float4 chunks -> bf16x4 ds_write

  for (int k0 = 0; k0 < K; k0 += 32) {
    async16(Ab + (size_t)arow * K + k0 + ac, &As[arow][ac]);
    async16(Ab + (size_t)(arow + 64) * K + k0 + ac, &As[arow + 64][ac]);
    #pragma unroll
    for (int i = 0; i < NT / 32; ++i) {
      const int rw = wrow + 32 * i;
      const floatx4 f = *(const floatx4*)(Wb + (size_t)rw * K + k0 + wc4);
      bf16x4 h4 = { (__bf16)f[0], (__bf16)f[1], (__bf16)f[2], (__bf16)f[3] };
      *(bf16x4*)&Ws[rw][wc4] = h4;
    }
    __syncthreads();
    bf16x8 af[4];
    #pragma unroll
    for (int mi = 0; mi < 4; ++mi)
      af[mi] = *(const bf16x8*)&As[wr * 64 + mi * 16 + r][quad * 8];
    #pragma unroll
    for (int ni = 0; ni < NACC; ++ni) {
      bf16x8 bf = *(const bf16x8*)&Ws[wc * (NT / 2) + ni * 16 + r][quad * 8];
      #pragma unroll
      for (int mi = 0; mi < 4; ++mi)
        acc[mi][ni] = __builtin_amdgcn_mfma_f32_16x16x32_bf16(af[mi], bf, acc[mi][ni], 0, 0, 0);
    }
    __syncthreads();
  }

  // epilogue: C/D layout col=lane&15, row=quad*4+reg
  #pragma unroll
  for (int ni = 0; ni < NACC; ++ni) {
    const int nn = n0 + wc * (NT / 2) + ni * 16 + r;
    const float bv = bias[nn];
    #pragma unroll
    for (int mi = 0; mi < 4; ++mi) {
      #pragma unroll
      for (int v = 0; v < 4; ++v) {
        const int mm = m0 + wr * 64 + mi * 16 + quad * 4 + v;
        float val = acc[mi][ni][v] + bv;
        if (MODE == EPI_GELU) {
          val = 0.5f * val * (1.0f + erff(val * 0.70710678118654752f));
          ((__bf16*)out)[(size_t)mm * N + nn] = (__bf16)val;
        } else if (MODE == EPI_RES) {
          ((float*)out)[(size_t)mm * N + nn] = res[(size_t)mm * N + nn] + val;
        } else if (MODE == EPI_QKV) {
          if (nn < 2048) {
            // fold 1/sqrt(HD)=0.125 into Q so attention skips the scale fma
            const float sv = (nn < 1024) ? val * 0.125f : val;
            ((__bf16*)out)[(size_t)mm * 2048 + nn] = (__bf16)sv;
          } else {
            const int c = nn - 2048, hh = c >> 6, dd = c & 63;
            const int bb = mm >> 11, t = mm & 2047;
            vT[(size_t)((bb * 16 + hh) * 64 + dd) * 2048 + t] = (__bf16)val;
          }
        }
      }
    }
  }
}

// ---------- Flash attention, transposed-MFMA formulation, 64-key tiles ----------
// S^T = K.Q^T (col = query = lane&15). P^T transposed C->B layout via wave-private
// LDS (ds_write_b64 rows of 4 keys, ds_read_b128 B-frags; 64B rows = conflict-free).
// O^T = V^T.P^T. grid: x = B*H, y = qt_raw (remapped for per-CU causal load balance).
__global__ __launch_bounds__(256, 4)
void attn_kernel(const __bf16* __restrict__ qk,  // [B*T][2048]: cols 0..1023 Q(*0.125), 1024..2047 K
                 const __bf16* __restrict__ vT,  // [(b*16+h)*64+d][2048]
                 __bf16* __restrict__ out)       // [B*T][1024]
{
  __shared__ __align__(16) __bf16 Qs[2][64][32];     // [d-half][q][d]     8 KB
  __shared__ __align__(16) __bf16 Ks[2][64][32];     // [d-half][key][d]   8 KB
  __shared__ __align__(16) __bf16 Vs[2][64][32];     // [key-blk][d][key]  8 KB
  __shared__ __align__(16) __bf16 Ps[4][2][16][32];  // [wave][key-blk][q][key] 8 KB (32 KB tot)
  const int tid = threadIdx.x, lane = tid & 63, w = tid >> 6;
  const int quad = lane >> 4, r = lane & 15;
  const int bh = blockIdx.x, b = bh >> 4, h = bh & 15;
  // balanced remap: CU's round-robin set {j,15-j,16+j,31-j} -> sum(qt+1)=66 const
  const int yk = blockIdx.y >> 3, yj = blockIdx.y & 7;
  const int qt = (yk << 3) | ((yk & 1) ? (7 - yj) : yj);
  const int q0 = qt * 64;

  { // stage Q both halves: 512 chunks, LDS flat offset = 16B * chunk (wave-contiguous)
    const __bf16* qb = qk + ((size_t)(b * SEQ + q0)) * 2048 + h * 64;
    #pragma unroll
    for (int rd = 0; rd < 2; ++rd) {
      const int c = rd * 256 + tid, half = c >> 8, row = (c >> 2) & 63, c8 = (c & 3) * 8;
      async16(qb + (size_t)row * 2048 + half * 32 + c8, &Qs[half][row][c8]);
    }
  }
  __syncthreads();
  const bf16x8 qf0 = *(const bf16x8*)&Qs[0][w * 16 + r][quad * 8];
  const bf16x8 qf1 = *(const bf16x8*)&Qs[1][w * 16 + r][quad * 8];

  const int q = q0 + w * 16 + r;                   // this lane's query row
  float m_i = -INFINITY, l_i = 0.0f;
  floatx4 ot[4] = {};
  const float slope = exp2f(-0.5f * (float)(h + 1));
  const float sq = slope * (float)q;

  const __bf16* kb0 = qk + ((size_t)(b * SEQ)) * 2048 + 1024 + h * 64;
  const __bf16* vb0 = vT + ((size_t)(bh * 64)) * 2048;

  for (int kt = 0; kt <= qt; ++kt) {
    const int kbase = kt << 6;
    #pragma unroll
    for (int rd = 0; rd < 2; ++rd) {
      const int c = rd * 256 + tid, half = c >> 8, row = (c >> 2) & 63, c8 = (c & 3) * 8;
      async16(kb0 + (size_t)(kbase + row) * 2048 + half * 32 + c8, &Ks[half][row][c8]);
    }
    #pragma unroll
    for (int rd = 0; rd < 2; ++rd) {
      const int c = rd * 256 + tid, kb = c >> 8, d = (c >> 2) & 63, c8 = (c & 3) * 8;
      async16(vb0 + (size_t)d * 2048 + kbase + kb * 32 + c8, &Vs[kb][d][c8]);
    }
    __syncthreads();

    // S^T tiles: st[t] keys kbase+t*16+quad*4+v, col q=r (Q pre-scaled by 0.125)
    floatx4 st[4];
    #pragma unroll
    for (int t = 0; t < 4; ++t) {
      floatx4 z = { 0.0f, 0.0f, 0.0f, 0.0f };
      const bf16x8 kf0 = *(const bf16x8*)&Ks[0][t * 16 + r][quad * 8];
      const bf16x8 kf1 = *(const bf16x8*)&Ks[1][t * 16 + r][quad * 8];
      z = __builtin_amdgcn_mfma_f32_16x16x32_bf16(kf0, qf0, z, 0, 0, 0);
      st[t] = __builtin_amdgcn_mfma_f32_16x16x32_bf16(kf1, qf1, st[t] = z, 0, 0, 0);
    }
    // alibi always; causal cndmask only on the diagonal tile
    float mloc = -INFINITY;
    if (kt == qt) {
      #pragma unroll
      for (int t = 0; t < 4; ++t)
        #pragma unroll
        for (int v = 0; v < 4; ++v) {
          const int key = kbase + t * 16 + quad * 4 + v;
          float sv = st[t][v] + slope * (float)key - sq;
          sv = (key <= q) ? sv : -INFINITY;
          st[t][v] = sv;
          mloc = fmaxf(mloc, sv);
        }
    } else {
      #pragma unroll
      for (int t = 0; t < 4; ++t)
        #pragma unroll
        for (int v = 0; v < 4; ++v) {
          const int key = kbase + t * 16 + quad * 4 + v;
          const float sv = st[t][v] + slope * (float)key - sq;
          st[t][v] = sv;
          mloc = fmaxf(mloc, sv);
        }
    }
    mloc = fmaxf(mloc, __shfl_xor(mloc, 16));
    mloc = fmaxf(mloc, __shfl_xor(mloc, 32));
    const float mn = fmaxf(m_i, mloc);
    const float alpha = __expf(m_i - mn);   // first tile: exp(-inf)=0
    m_i = mn;
    float rsum = 0.0f;
    #pragma unroll
    for (int t = 0; t < 4; ++t) {
      bf16x4 p4;
      #pragma unroll
      for (int v = 0; v < 4; ++v) {
        const float p = __expf(st[t][v] - mn);
        rsum += p;
        p4[v] = (__bf16)p;
      }
      // C-layout row = 4 consecutive keys -> one b64 write into Ps[w][kb][q][key%32]
      *(bf16x4*)&Ps[w][t >> 1][r][(t & 1) * 16 + quad * 4] = p4;
    }
    rsum += __shfl_xor(rsum, 16);
    rsum += __shfl_xor(rsum, 32);
    l_i = l_i * alpha + rsum;
    #pragma unroll
    for (int dt = 0; dt < 4; ++dt) ot[dt] *= alpha;

    // O^T += V^T . P^T  (A-frag from Vs, B-frag straight from Ps)
    #pragma unroll
    for (int kb = 0; kb < 2; ++kb) {
      const bf16x8 pf = *(const bf16x8*)&Ps[w][kb][r][quad * 8];
      #pragma unroll
      for (int dt = 0; dt < 4; ++dt) {
        const bf16x8 vf = *(const bf16x8*)&Vs[kb][dt * 16 + r][quad * 8];
        ot[dt] = __builtin_amdgcn_mfma_f32_16x16x32_bf16(vf, pf, ot[dt], 0, 0, 0);
      }
    }
    __syncthreads();
  }

  // O^T C-layout: col = q = r (lane), row = d = dt*16 + quad*4 + v -> bf16x4 stores
  const float linv = 1.0f / l_i;
  __bf16* ob = out + (size_t)(b * SEQ + q) * D_MODEL + h * 64;
  #pragma unroll
  for (int dt = 0; dt < 4; ++dt) {
    bf16x4 o4 = { (__bf16)(ot[dt][0] * linv), (__bf16)(ot[dt][1] * linv),
                  (__bf16)(ot[dt][2] * linv), (__bf16)(ot[dt][3] * linv) };
    *(bf16x4*)(ob + dt * 16 + quad * 4) = o4;
  }
}

// ---------- driver ----------
extern "C" void kernel_launch(void* const* d_in, const int* in_sizes, int n_in,
                              void* d_out, int out_size, void* d_ws, size_t ws_size,
                              hipStream_t stream)
{
  (void)in_sizes; (void)n_in; (void)out_size; (void)ws_size;
  const float* x    = (const float*)d_in[0];
  const float* inW  = (const float*)d_in[1];
  const float* inB  = (const float*)d_in[2];
  const float* outW = (const float*)d_in[3];
  const float* outB = (const float*)d_in[4];
  const float* f1W  = (const float*)d_in[5];
  const float* f1B  = (const float*)d_in[6];
  const float* f2W  = (const float*)d_in[7];
  const float* f2B  = (const float*)d_in[8];
  const float* ln1W = (const float*)d_in[9];
  const float* ln1B = (const float*)d_in[10];
  const float* ln2W = (const float*)d_in[11];
  const float* ln2B = (const float*)d_in[12];
  const float* fnW  = (const float*)d_in[13];
  const float* fnB  = (const float*)d_in[14];

  char* ws = (char*)d_ws;
  float*  x_cur = (float*)(ws);                    // 16.78 MB fp32 residual
  __bf16* xn    = (__bf16*)(ws + 16777216);        //  8.39 MB
  __bf16* qk    = (__bf16*)(ws + 25165824);        // 16.78 MB
  __bf16* vT    = (__bf16*)(ws + 41943040);        //  8.39 MB
  __bf16* attn  = (__bf16*)(ws + 50331648);        //  8.39 MB
  __bf16* hbuf  = (__bf16*)(ws + 25165824);        // 33.55 MB, aliases qk/vT/attn (dead by FFN1)
  // total footprint: 56 MB

  hipMemcpyAsync(x_cur, x, (size_t)16777216, hipMemcpyDeviceToDevice, stream);

  for (int i = 0; i < 4; ++i) {
    ln_kernel<true><<<dim3(4096), dim3(256), 0, stream>>>(
        x_cur, ln1W + i * 1024, ln1B + i * 1024, xn);
    gemm_kernel<EPI_QKV, 128><<<dim3(32, 24), dim3(256), 0, stream>>>(
        xn, inW + (size_t)i * 3072 * 1024, inB + (size_t)i * 3072,
        qk, nullptr, vT, 4096, 3072, 1024);
    attn_kernel<<<dim3(32, 32), dim3(256), 0, stream>>>(qk, vT, attn);
    gemm_kernel<EPI_RES, 64><<<dim3(32, 16), dim3(256), 0, stream>>>(
        attn, outW + (size_t)i * 1024 * 1024, outB + (size_t)i * 1024,
        x_cur, x_cur, nullptr, 4096, 1024, 1024);
    ln_kernel<true><<<dim3(4096), dim3(256), 0, stream>>>(
        x_cur, ln2W + i * 1024, ln2B + i * 1024, xn);
    gemm_kernel<EPI_GELU, 128><<<dim3(32, 32), dim3(256), 0, stream>>>(
        xn, f1W + (size_t)i * 4096 * 1024, f1B + (size_t)i * 4096,
        hbuf, nullptr, nullptr, 4096, 4096, 1024);
    gemm_kernel<EPI_RES, 64><<<dim3(32, 16), dim3(256), 0, stream>>>(
        hbuf, f2W + (size_t)i * 1024 * 4096, f2B + (size_t)i * 1024,
        x_cur, x_cur, nullptr, 4096, 1024, 4096);
  }
  ln_kernel<false><<<dim3(4096), dim3(256), 0, stream>>>(x_cur, fnW, fnB, d_out);
}

// Round 6
// 1237.216 us; speedup vs baseline: 1.7907x; 1.3034x over previous
//
#include <hip/hip_runtime.h>
#include <hip/hip_bf16.h>
#include <math.h>

// ---------- types ----------
typedef __bf16 bf16x8 __attribute__((ext_vector_type(8)));
typedef __bf16 bf16x4 __attribute__((ext_vector_type(4)));
typedef float  floatx4 __attribute__((ext_vector_type(4)));

#define D_MODEL 1024
#define SEQ     2048
#define NHEAD   16
#define HD      64

__device__ __forceinline__ void async16(const void* g, void* l) {
  __builtin_amdgcn_global_load_lds((const __attribute__((address_space(1))) void*)g,
                                   (__attribute__((address_space(3))) void*)l, 16, 0, 0);
}

// ---------- weight fp32 -> bf16 convert ----------
__global__ __launch_bounds__(256)
void cvtw_kernel(const float* __restrict__ in, __bf16* __restrict__ out) {
  const size_t i = ((size_t)blockIdx.x * 256 + threadIdx.x) * 4;
  const floatx4 f = *(const floatx4*)(in + i);
  bf16x4 o = { (__bf16)f[0], (__bf16)f[1], (__bf16)f[2], (__bf16)f[3] };
  *(bf16x4*)(out + i) = o;
}

// ---------- LayerNorm: fp32 row(1024) -> bf16 (or fp32 for final) ----------
template<bool OUT_BF16>
__global__ __launch_bounds__(256)
void ln_kernel(const float* __restrict__ x, const float* __restrict__ w,
               const float* __restrict__ b, void* __restrict__ out)
{
  const int row = blockIdx.x;
  const int tid = threadIdx.x;
  const floatx4 f = *(const floatx4*)(x + (size_t)row * D_MODEL + tid * 4);
  float s = f[0] + f[1] + f[2] + f[3];
  #pragma unroll
  for (int off = 1; off < 64; off <<= 1) s += __shfl_xor(s, off);
  __shared__ float red[8];
  const int wv = tid >> 6;
  if ((tid & 63) == 0) red[wv] = s;
  __syncthreads();
  const float mu = (red[0] + red[1] + red[2] + red[3]) * (1.0f / 1024.0f);
  float d0 = f[0] - mu, d1 = f[1] - mu, d2 = f[2] - mu, d3 = f[3] - mu;
  float ss = d0 * d0 + d1 * d1 + d2 * d2 + d3 * d3;
  #pragma unroll
  for (int off = 1; off < 64; off <<= 1) ss += __shfl_xor(ss, off);
  if ((tid & 63) == 0) red[4 + wv] = ss;
  __syncthreads();
  const float rstd = rsqrtf((red[4] + red[5] + red[6] + red[7]) * (1.0f / 1024.0f) + 1e-5f);
  const floatx4 wv4 = *(const floatx4*)(w + tid * 4);
  const floatx4 bv4 = *(const floatx4*)(b + tid * 4);
  const float y0 = d0 * rstd * wv4[0] + bv4[0];
  const float y1 = d1 * rstd * wv4[1] + bv4[1];
  const float y2 = d2 * rstd * wv4[2] + bv4[2];
  const float y3 = d3 * rstd * wv4[3] + bv4[3];
  if (OUT_BF16) {
    bf16x4 o = { (__bf16)y0, (__bf16)y1, (__bf16)y2, (__bf16)y3 };
    *(bf16x4*)((__bf16*)out + (size_t)row * D_MODEL + tid * 4) = o;
  } else {
    floatx4 o = { y0, y1, y2, y3 };
    *(floatx4*)((float*)out + (size_t)row * D_MODEL + tid * 4) = o;
  }
}

#define EPI_GELU 1
#define EPI_RES  2
#define EPI_QKV  3

// ---------- GEMM128 (bf16 W): m97 structure, 128x128 tile, BK=32 ----------
template<int MODE>
__global__ __launch_bounds__(256, 2)
void gemm128_kernel(const __bf16* __restrict__ A, const __bf16* __restrict__ W,
                    const float* __restrict__ bias, void* out,
                    __bf16* __restrict__ vT, int M, int N, int K)
{
  __shared__ __align__(16) __bf16 As[128][32];  // 8 KB (64B rows: conflict-free b128)
  __shared__ __align__(16) __bf16 Ws[128][32];  // 8 KB
  const int tid = threadIdx.x;
  const int lane = tid & 63, w = tid >> 6;
  const int wr = w >> 1, wc = w & 1;
  const int quad = lane >> 4, r = lane & 15;
  const int m0 = blockIdx.x * 128, n0 = blockIdx.y * 128;

  floatx4 acc[4][4] = {};

  const __bf16* Ab = A + (size_t)m0 * K;
  const __bf16* Wb = W + (size_t)n0 * K;
  const int sr = tid >> 2, sc = (tid & 3) * 8;   // 16B chunks, lane*16 LDS-contiguous

  for (int k0 = 0; k0 < K; k0 += 32) {
    async16(Ab + (size_t)sr * K + k0 + sc, &As[sr][sc]);
    async16(Ab + (size_t)(sr + 64) * K + k0 + sc, &As[sr + 64][sc]);
    async16(Wb + (size_t)sr * K + k0 + sc, &Ws[sr][sc]);
    async16(Wb + (size_t)(sr + 64) * K + k0 + sc, &Ws[sr + 64][sc]);
    __syncthreads();
    bf16x8 af[4];
    #pragma unroll
    for (int mi = 0; mi < 4; ++mi)
      af[mi] = *(const bf16x8*)&As[wr * 64 + mi * 16 + r][quad * 8];
    #pragma unroll
    for (int ni = 0; ni < 4; ++ni) {
      const bf16x8 bf = *(const bf16x8*)&Ws[wc * 64 + ni * 16 + r][quad * 8];
      #pragma unroll
      for (int mi = 0; mi < 4; ++mi)
        acc[mi][ni] = __builtin_amdgcn_mfma_f32_16x16x32_bf16(af[mi], bf, acc[mi][ni], 0, 0, 0);
    }
    __syncthreads();
  }

  // epilogue: C/D layout col=lane&15, row=quad*4+reg
  #pragma unroll
  for (int ni = 0; ni < 4; ++ni) {
    const int nn = n0 + wc * 64 + ni * 16 + r;
    const float bv = bias[nn];
    #pragma unroll
    for (int mi = 0; mi < 4; ++mi) {
      #pragma unroll
      for (int v = 0; v < 4; ++v) {
        const int mm = m0 + wr * 64 + mi * 16 + quad * 4 + v;
        float val = acc[mi][ni][v] + bv;
        if (MODE == EPI_GELU) {
          val = 0.5f * val * (1.0f + erff(val * 0.70710678118654752f));
          ((__bf16*)out)[(size_t)mm * N + nn] = (__bf16)val;
        } else if (MODE == EPI_QKV) {
          if (nn < 2048) {
            const float sv = (nn < 1024) ? val * 0.125f : val;  // fold 1/sqrt(HD) into Q
            ((__bf16*)out)[(size_t)mm * 2048 + nn] = (__bf16)sv;
          } else {
            const int c = nn - 2048, hh = c >> 6, dd = c & 63;
            const int bb = mm >> 11, t = mm & 2047;
            vT[(size_t)((bb * 16 + hh) * 64 + dd) * 2048 + t] = (__bf16)val;
          }
        }
      }
    }
  }
}

// ---------- GEMM64 (bf16 W): 128x64 tile, BK=64, EPI_RES; k-halves split ----------
__global__ __launch_bounds__(256, 2)
void gemm64_kernel(const __bf16* __restrict__ A, const __bf16* __restrict__ W,
                   const float* __restrict__ bias, float* __restrict__ out,
                   const float* __restrict__ res, int M, int N, int K)
{
  __shared__ __align__(16) __bf16 As0[128][32], As1[128][32];  // 16 KB
  __shared__ __align__(16) __bf16 Ws0[64][32],  Ws1[64][32];   //  8 KB
  const int tid = threadIdx.x;
  const int lane = tid & 63, w = tid >> 6;
  const int wr = w >> 1, wc = w & 1;
  const int quad = lane >> 4, r = lane & 15;
  const int m0 = blockIdx.x * 128, n0 = blockIdx.y * 64;

  floatx4 acc[4][2] = {};

  const __bf16* Ab = A + (size_t)m0 * K;
  const __bf16* Wb = W + (size_t)n0 * K;
  const int sr = tid >> 2, sc = (tid & 3) * 8;

  for (int k0 = 0; k0 < K; k0 += 64) {
    async16(Ab + (size_t)sr * K + k0 + sc,             &As0[sr][sc]);
    async16(Ab + (size_t)(sr + 64) * K + k0 + sc,      &As0[sr + 64][sc]);
    async16(Ab + (size_t)sr * K + k0 + 32 + sc,        &As1[sr][sc]);
    async16(Ab + (size_t)(sr + 64) * K + k0 + 32 + sc, &As1[sr + 64][sc]);
    async16(Wb + (size_t)sr * K + k0 + sc,             &Ws0[sr][sc]);
    async16(Wb + (size_t)sr * K + k0 + 32 + sc,        &Ws1[sr][sc]);
    __syncthreads();
    bf16x8 af0[4], af1[4];
    #pragma unroll
    for (int mi = 0; mi < 4; ++mi) {
      af0[mi] = *(const bf16x8*)&As0[wr * 64 + mi * 16 + r][quad * 8];
      af1[mi] = *(const bf16x8*)&As1[wr * 64 + mi * 16 + r][quad * 8];
    }
    #pragma unroll
    for (int ni = 0; ni < 2; ++ni) {
      const bf16x8 b0 = *(const bf16x8*)&Ws0[wc * 32 + ni * 16 + r][quad * 8];
      const bf16x8 b1 = *(const bf16x8*)&Ws1[wc * 32 + ni * 16 + r][quad * 8];
      #pragma unroll
      for (int mi = 0; mi < 4; ++mi) {
        acc[mi][ni] = __builtin_amdgcn_mfma_f32_16x16x32_bf16(af0[mi], b0, acc[mi][ni], 0, 0, 0);
        acc[mi][ni] = __builtin_amdgcn_mfma_f32_16x16x32_bf16(af1[mi], b1, acc[mi][ni], 0, 0, 0);
      }
    }
    __syncthreads();
  }

  #pragma unroll
  for (int ni = 0; ni < 2; ++ni) {
    const int nn = n0 + wc * 32 + ni * 16 + r;
    const float bv = bias[nn];
    #pragma unroll
    for (int mi = 0; mi < 4; ++mi) {
      #pragma unroll
      for (int v = 0; v < 4; ++v) {
        const int mm = m0 + wr * 64 + mi * 16 + quad * 4 + v;
        out[(size_t)mm * N + nn] = res[(size_t)mm * N + nn] + acc[mi][ni][v] + bv;
      }
    }
  }
}

// ---------- LEGACY GEMM (fp32 W) — fallback if workspace too small ----------
template<int MODE, int NT>
__global__ __launch_bounds__(256, 2)
void gemm_legacy_kernel(const __bf16* __restrict__ A, const float* __restrict__ W,
                        const float* __restrict__ bias, void* out,
                        const float* __restrict__ res, __bf16* __restrict__ vT,
                        int M, int N, int K)
{
  __shared__ __align__(16) __bf16 As[128][32];
  __shared__ __align__(16) __bf16 Ws[NT][32];
  const int tid = threadIdx.x;
  const int lane = tid & 63, w = tid >> 6;
  const int wr = w >> 1, wc = w & 1;
  const int quad = lane >> 4, r = lane & 15;
  constexpr int NACC = NT / 32;
  const int m0 = blockIdx.x * 128, n0 = blockIdx.y * NT;
  floatx4 acc[4][NACC] = {};
  const __bf16* Ab = A + (size_t)m0 * K;
  const float*  Wb = W + (size_t)n0 * K;
  const int arow = tid >> 2, ac = (tid & 3) * 8;
  const int wrow = tid >> 3, wc4 = (tid & 7) * 4;
  for (int k0 = 0; k0 < K; k0 += 32) {
    async16(Ab + (size_t)arow * K + k0 + ac, &As[arow][ac]);
    async16(Ab + (size_t)(arow + 64) * K + k0 + ac, &As[arow + 64][ac]);
    #pragma unroll
    for (int i = 0; i < NT / 32; ++i) {
      const int rw = wrow + 32 * i;
      const floatx4 f = *(const floatx4*)(Wb + (size_t)rw * K + k0 + wc4);
      bf16x4 h4 = { (__bf16)f[0], (__bf16)f[1], (__bf16)f[2], (__bf16)f[3] };
      *(bf16x4*)&Ws[rw][wc4] = h4;
    }
    __syncthreads();
    bf16x8 af[4];
    #pragma unroll
    for (int mi = 0; mi < 4; ++mi)
      af[mi] = *(const bf16x8*)&As[wr * 64 + mi * 16 + r][quad * 8];
    #pragma unroll
    for (int ni = 0; ni < NACC; ++ni) {
      bf16x8 bf = *(const bf16x8*)&Ws[wc * (NT / 2) + ni * 16 + r][quad * 8];
      #pragma unroll
      for (int mi = 0; mi < 4; ++mi)
        acc[mi][ni] = __builtin_amdgcn_mfma_f32_16x16x32_bf16(af[mi], bf, acc[mi][ni], 0, 0, 0);
    }
    __syncthreads();
  }
  #pragma unroll
  for (int ni = 0; ni < NACC; ++ni) {
    const int nn = n0 + wc * (NT / 2) + ni * 16 + r;
    const float bv = bias[nn];
    #pragma unroll
    for (int mi = 0; mi < 4; ++mi) {
      #pragma unroll
      for (int v = 0; v < 4; ++v) {
        const int mm = m0 + wr * 64 + mi * 16 + quad * 4 + v;
        float val = acc[mi][ni][v] + bv;
        if (MODE == EPI_GELU) {
          val = 0.5f * val * (1.0f + erff(val * 0.70710678118654752f));
          ((__bf16*)out)[(size_t)mm * N + nn] = (__bf16)val;
        } else if (MODE == EPI_RES) {
          ((float*)out)[(size_t)mm * N + nn] = res[(size_t)mm * N + nn] + val;
        } else if (MODE == EPI_QKV) {
          if (nn < 2048) {
            const float sv = (nn < 1024) ? val * 0.125f : val;
            ((__bf16*)out)[(size_t)mm * 2048 + nn] = (__bf16)sv;
          } else {
            const int c = nn - 2048, hh = c >> 6, dd = c & 63;
            const int bb = mm >> 11, t = mm & 2047;
            vT[(size_t)((bb * 16 + hh) * 64 + dd) * 2048 + t] = (__bf16)val;
          }
        }
      }
    }
  }
}

// ---------- Flash attention, transposed-MFMA formulation, 64-key tiles ----------
__global__ __launch_bounds__(256, 4)
void attn_kernel(const __bf16* __restrict__ qk,  // [B*T][2048]: cols 0..1023 Q(*0.125), 1024..2047 K
                 const __bf16* __restrict__ vT,  // [(b*16+h)*64+d][2048]
                 __bf16* __restrict__ out)       // [B*T][1024]
{
  __shared__ __align__(16) __bf16 Qs[2][64][32];
  __shared__ __align__(16) __bf16 Ks[2][64][32];
  __shared__ __align__(16) __bf16 Vs[2][64][32];
  __shared__ __align__(16) __bf16 Ps[4][2][16][32];
  const int tid = threadIdx.x, lane = tid & 63, w = tid >> 6;
  const int quad = lane >> 4, r = lane & 15;
  const int bh = blockIdx.x, b = bh >> 4, h = bh & 15;
  const int yk = blockIdx.y >> 3, yj = blockIdx.y & 7;
  const int qt = (yk << 3) | ((yk & 1) ? (7 - yj) : yj);
  const int q0 = qt * 64;

  {
    const __bf16* qb = qk + ((size_t)(b * SEQ + q0)) * 2048 + h * 64;
    #pragma unroll
    for (int rd = 0; rd < 2; ++rd) {
      const int c = rd * 256 + tid, half = c >> 8, row = (c >> 2) & 63, c8 = (c & 3) * 8;
      async16(qb + (size_t)row * 2048 + half * 32 + c8, &Qs[half][row][c8]);
    }
  }
  __syncthreads();
  const bf16x8 qf0 = *(const bf16x8*)&Qs[0][w * 16 + r][quad * 8];
  const bf16x8 qf1 = *(const bf16x8*)&Qs[1][w * 16 + r][quad * 8];

  const int q = q0 + w * 16 + r;
  float m_i = -INFINITY, l_i = 0.0f;
  floatx4 ot[4] = {};
  const float slope = exp2f(-0.5f * (float)(h + 1));
  const float sq = slope * (float)q;

  const __bf16* kb0 = qk + ((size_t)(b * SEQ)) * 2048 + 1024 + h * 64;
  const __bf16* vb0 = vT + ((size_t)(bh * 64)) * 2048;

  for (int kt = 0; kt <= qt; ++kt) {
    const int kbase = kt << 6;
    #pragma unroll
    for (int rd = 0; rd < 2; ++rd) {
      const int c = rd * 256 + tid, half = c >> 8, row = (c >> 2) & 63, c8 = (c & 3) * 8;
      async16(kb0 + (size_t)(kbase + row) * 2048 + half * 32 + c8, &Ks[half][row][c8]);
    }
    #pragma unroll
    for (int rd = 0; rd < 2; ++rd) {
      const int c = rd * 256 + tid, kb = c >> 8, d = (c >> 2) & 63, c8 = (c & 3) * 8;
      async16(vb0 + (size_t)d * 2048 + kbase + kb * 32 + c8, &Vs[kb][d][c8]);
    }
    __syncthreads();

    floatx4 st[4];
    #pragma unroll
    for (int t = 0; t < 4; ++t) {
      floatx4 z = { 0.0f, 0.0f, 0.0f, 0.0f };
      const bf16x8 kf0 = *(const bf16x8*)&Ks[0][t * 16 + r][quad * 8];
      const bf16x8 kf1 = *(const bf16x8*)&Ks[1][t * 16 + r][quad * 8];
      z = __builtin_amdgcn_mfma_f32_16x16x32_bf16(kf0, qf0, z, 0, 0, 0);
      st[t] = __builtin_amdgcn_mfma_f32_16x16x32_bf16(kf1, qf1, z, 0, 0, 0);
    }
    float mloc = -INFINITY;
    if (kt == qt) {
      #pragma unroll
      for (int t = 0; t < 4; ++t)
        #pragma unroll
        for (int v = 0; v < 4; ++v) {
          const int key = kbase + t * 16 + quad * 4 + v;
          float sv = st[t][v] + slope * (float)key - sq;
          sv = (key <= q) ? sv : -INFINITY;
          st[t][v] = sv;
          mloc = fmaxf(mloc, sv);
        }
    } else {
      #pragma unroll
      for (int t = 0; t < 4; ++t)
        #pragma unroll
        for (int v = 0; v < 4; ++v) {
          const int key = kbase + t * 16 + quad * 4 + v;
          const float sv = st[t][v] + slope * (float)key - sq;
          st[t][v] = sv;
          mloc = fmaxf(mloc, sv);
        }
    }
    mloc = fmaxf(mloc, __shfl_xor(mloc, 16));
    mloc = fmaxf(mloc, __shfl_xor(mloc, 32));
    const float mn = fmaxf(m_i, mloc);
    const float alpha = __expf(m_i - mn);
    m_i = mn;
    float rsum = 0.0f;
    #pragma unroll
    for (int t = 0; t < 4; ++t) {
      bf16x4 p4;
      #pragma unroll
      for (int v = 0; v < 4; ++v) {
        const float p = __expf(st[t][v] - mn);
        rsum += p;
        p4[v] = (__bf16)p;
      }
      *(bf16x4*)&Ps[w][t >> 1][r][(t & 1) * 16 + quad * 4] = p4;
    }
    rsum += __shfl_xor(rsum, 16);
    rsum += __shfl_xor(rsum, 32);
    l_i = l_i * alpha + rsum;
    #pragma unroll
    for (int dt = 0; dt < 4; ++dt) ot[dt] *= alpha;

    #pragma unroll
    for (int kb = 0; kb < 2; ++kb) {
      const bf16x8 pf = *(const bf16x8*)&Ps[w][kb][r][quad * 8];
      #pragma unroll
      for (int dt = 0; dt < 4; ++dt) {
        const bf16x8 vf = *(const bf16x8*)&Vs[kb][dt * 16 + r][quad * 8];
        ot[dt] = __builtin_amdgcn_mfma_f32_16x16x32_bf16(vf, pf, ot[dt], 0, 0, 0);
      }
    }
    __syncthreads();
  }

  const float linv = 1.0f / l_i;
  __bf16* ob = out + (size_t)(b * SEQ + q) * D_MODEL + h * 64;
  #pragma unroll
  for (int dt = 0; dt < 4; ++dt) {
    bf16x4 o4 = { (__bf16)(ot[dt][0] * linv), (__bf16)(ot[dt][1] * linv),
                  (__bf16)(ot[dt][2] * linv), (__bf16)(ot[dt][3] * linv) };
    *(bf16x4*)(ob + dt * 16 + quad * 4) = o4;
  }
}

// ---------- driver ----------
extern "C" void kernel_launch(void* const* d_in, const int* in_sizes, int n_in,
                              void* d_out, int out_size, void* d_ws, size_t ws_size,
                              hipStream_t stream)
{
  (void)in_sizes; (void)n_in; (void)out_size;
  const float* x    = (const float*)d_in[0];
  const float* inW  = (const float*)d_in[1];
  const float* inB  = (const float*)d_in[2];
  const float* outW = (const float*)d_in[3];
  const float* outB = (const float*)d_in[4];
  const float* f1W  = (const float*)d_in[5];
  const float* f1B  = (const float*)d_in[6];
  const float* f2W  = (const float*)d_in[7];
  const float* f2B  = (const float*)d_in[8];
  const float* ln1W = (const float*)d_in[9];
  const float* ln1B = (const float*)d_in[10];
  const float* ln2W = (const float*)d_in[11];
  const float* ln2B = (const float*)d_in[12];
  const float* fnW  = (const float*)d_in[13];
  const float* fnB  = (const float*)d_in[14];

  char* ws = (char*)d_ws;
  float*  x_cur = (float*)(ws);                    // 16.78 MB fp32 residual
  __bf16* xn    = (__bf16*)(ws + 16777216);        //  8.39 MB
  __bf16* qk    = (__bf16*)(ws + 25165824);        // 16.78 MB
  __bf16* vT    = (__bf16*)(ws + 41943040);        //  8.39 MB
  __bf16* attn  = (__bf16*)(ws + 50331648);        //  8.39 MB
  __bf16* hbuf  = (__bf16*)(ws + 25165824);        // 33.55 MB, aliases qk/vT/attn (dead by FFN1)
  // bf16 weight cache (one-time convert per launch)
  __bf16* inWb  = (__bf16*)(ws + 58720256);        // 25.17 MB
  __bf16* outWb = (__bf16*)(ws + 83886080);        //  8.39 MB
  __bf16* f1Wb  = (__bf16*)(ws + 92274688);        // 33.55 MB
  __bf16* f2Wb  = (__bf16*)(ws + 125829120);       // 33.55 MB -> need 159,383,552 B
  const bool bf16w = ws_size >= (size_t)159383552;

  hipMemcpyAsync(x_cur, x, (size_t)16777216, hipMemcpyDeviceToDevice, stream);

  if (bf16w) {
    cvtw_kernel<<<dim3(12288), dim3(256), 0, stream>>>(inW,  inWb);
    cvtw_kernel<<<dim3(4096),  dim3(256), 0, stream>>>(outW, outWb);
    cvtw_kernel<<<dim3(16384), dim3(256), 0, stream>>>(f1W,  f1Wb);
    cvtw_kernel<<<dim3(16384), dim3(256), 0, stream>>>(f2W,  f2Wb);
  }

  for (int i = 0; i < 4; ++i) {
    ln_kernel<true><<<dim3(4096), dim3(256), 0, stream>>>(
        x_cur, ln1W + i * 1024, ln1B + i * 1024, xn);
    if (bf16w)
      gemm128_kernel<EPI_QKV><<<dim3(32, 24), dim3(256), 0, stream>>>(
          xn, inWb + (size_t)i * 3072 * 1024, inB + (size_t)i * 3072,
          qk, vT, 4096, 3072, 1024);
    else
      gemm_legacy_kernel<EPI_QKV, 128><<<dim3(32, 24), dim3(256), 0, stream>>>(
          xn, inW + (size_t)i * 3072 * 1024, inB + (size_t)i * 3072,
          qk, nullptr, vT, 4096, 3072, 1024);
    attn_kernel<<<dim3(32, 32), dim3(256), 0, stream>>>(qk, vT, attn);
    if (bf16w)
      gemm64_kernel<<<dim3(32, 16), dim3(256), 0, stream>>>(
          attn, outWb + (size_t)i * 1024 * 1024, outB + (size_t)i * 1024,
          x_cur, x_cur, 4096, 1024, 1024);
    else
      gemm_legacy_kernel<EPI_RES, 64><<<dim3(32, 16), dim3(256), 0, stream>>>(
          attn, outW + (size_t)i * 1024 * 1024, outB + (size_t)i * 1024,
          x_cur, x_cur, nullptr, 4096, 1024, 1024);
    ln_kernel<true><<<dim3(4096), dim3(256), 0, stream>>>(
        x_cur, ln2W + i * 1024, ln2B + i * 1024, xn);
    if (bf16w)
      gemm128_kernel<EPI_GELU><<<dim3(32, 32), dim3(256), 0, stream>>>(
          xn, f1Wb + (size_t)i * 4096 * 1024, f1B + (size_t)i * 4096,
          hbuf, nullptr, 4096, 4096, 1024);
    else
      gemm_legacy_kernel<EPI_GELU, 128><<<dim3(32, 32), dim3(256), 0, stream>>>(
          xn, f1W + (size_t)i * 4096 * 1024, f1B + (size_t)i * 4096,
          hbuf, nullptr, nullptr, 4096, 4096, 1024);
    if (bf16w)
      gemm64_kernel<<<dim3(32, 16), dim3(256), 0, stream>>>(
          hbuf, f2Wb + (size_t)i * 1024 * 4096, f2B + (size_t)i * 1024,
          x_cur, x_cur, 4096, 1024, 4096);
    else
      gemm_legacy_kernel<EPI_RES, 64><<<dim3(32, 16), dim3(256), 0, stream>>>(
          hbuf, f2W + (size_t)i * 1024 * 4096, f2B + (size_t)i * 1024,
          x_cur, x_cur, nullptr, 4096, 1024, 4096);
  }
  ln_kernel<false><<<dim3(4096), dim3(256), 0, stream>>>(x_cur, fnW, fnB, d_out);
}